// Round 7
// baseline (404.799 us; speedup 1.0000x reference)
//
#include <hip/hip_runtime.h>
#include <hip/hip_bf16.h>
#include <math.h>

#define NROW 8
#define DT   2097152   // D = D1*D2
#define DD1  2048
#define DD2  1024
#define BATCH 512
#define NBLK 2048      // pass kernels: 2048 blocks x 256 thr x 4 cols == DT

// ws layout (~98.0 MiB):
//  [0)          mcode : NROW*DT uint8  level-2 m (+8 bias)
//  [16777216)   vsumb : NROW*DT bf16   final vsum, [n][k][l]
//  [50331648)   xb    : bf16 x
//  [67108864)   code  : DT bytes
//  [69206016)   wt    : NROW*DT bf16   [n][l][k]
//  [102760448)  meta  : u32[260]: hist2 @4, hist3 @132 (device-atomic RMW)
//  [102801408)  fin   : u32[4]: 0=SMAX fenc(max), 1=G2 bits, 2=G3 bits,
//                        3=~fenc(min) (max of complement == min; all init 0, ONE memset)

typedef __attribute__((ext_vector_type(8))) short short8;
typedef __attribute__((ext_vector_type(4))) float f32x4;

__device__ __forceinline__ unsigned fenc(float f){
  unsigned u = __float_as_uint(f);
  return (u & 0x80000000u) ? ~u : (u | 0x80000000u);
}
__device__ __forceinline__ float fdec(unsigned k){
  return (k & 0x80000000u) ? __uint_as_float(k ^ 0x80000000u) : __uint_as_float(~k);
}
__device__ __forceinline__ float s1_of(const unsigned* fin){
  #pragma clang fp contract(off)
  return (fdec(fin[0]) - fdec(~fin[3])) / 3.0f;   // identical expr to verified k_fin<0>
}
__device__ __forceinline__ float sigmoid_ref(float z){
  #pragma clang fp contract(off)
  return 1.0f / (1.0f + expf(-z));
}
__device__ __forceinline__ unsigned short f2bf(float f){
  __hip_bfloat16 h = __float2bfloat16(f);
  return *reinterpret_cast<unsigned short*>(&h);
}
// consistent level-1 base across ALL kernels
__device__ __forceinline__ float base1(float u, float s1, float inv_s1){
  #pragma clang fp contract(off)
  return s1 * floorf(u * inv_s1);
}
// reconstruct level-2 vsum from u + stored m byte (bit-exact vs producer)
__device__ __forceinline__ float vn2_of(float u, unsigned char mb, float s1, float inv_s1, float s2){
  #pragma clang fp contract(off)
  return base1(u, s1, inv_s1) + s2 * (float)((int)mb - 8);
}
__device__ __forceinline__ void async16(const unsigned short* g, unsigned short* l){
  __builtin_amdgcn_global_load_lds((const __attribute__((address_space(1))) unsigned int*)g,
                                   (__attribute__((address_space(3))) unsigned int*)l, 16, 0, 0);
}

// ---- 8-element sorting networks (Batcher odd-even, 19 comparators) ----
#define CSWAPV(a,b) { float _lo=fminf(a,b), _hi=fmaxf(a,b); a=_lo; b=_hi; }
__device__ __forceinline__ void sort8v(float v[8]){
  CSWAPV(v[0],v[1]) CSWAPV(v[2],v[3]) CSWAPV(v[4],v[5]) CSWAPV(v[6],v[7])
  CSWAPV(v[0],v[2]) CSWAPV(v[1],v[3]) CSWAPV(v[4],v[6]) CSWAPV(v[5],v[7])
  CSWAPV(v[1],v[2]) CSWAPV(v[5],v[6])
  CSWAPV(v[0],v[4]) CSWAPV(v[1],v[5]) CSWAPV(v[2],v[6]) CSWAPV(v[3],v[7])
  CSWAPV(v[2],v[4]) CSWAPV(v[3],v[5])
  CSWAPV(v[1],v[2]) CSWAPV(v[3],v[4]) CSWAPV(v[5],v[6])
}
__device__ __forceinline__ void cswapkv(float&av,int&ai,float&bv,int&bi){
  bool sw = (av > bv) || ((av == bv) && (ai > bi));   // lexicographic -> stable
  float nav = sw ? bv : av; float nbv = sw ? av : bv;
  int   nai = sw ? bi : ai; int   nbi = sw ? ai : bi;
  av = nav; bv = nbv; ai = nai; bi = nbi;
}
#define CSWAPK(i,j) cswapkv(v[i],ix[i],v[j],ix[j]);
__device__ __forceinline__ void sort8kv(float v[8], int ix[8]){
  CSWAPK(0,1) CSWAPK(2,3) CSWAPK(4,5) CSWAPK(6,7)
  CSWAPK(0,2) CSWAPK(1,3) CSWAPK(4,6) CSWAPK(5,7)
  CSWAPK(1,2) CSWAPK(5,6)
  CSWAPK(0,4) CSWAPK(1,5) CSWAPK(2,6) CSWAPK(3,7)
  CSWAPK(2,4) CSWAPK(3,5)
  CSWAPK(1,2) CSWAPK(3,4) CSWAPK(5,6)
}

// ---- P1: global min/max of U + x->bf16 + zero hists. All 12 loads issued before
// any dependent op (max memory-level parallelism; kernel was 58us @ 2.4% VALUBusy). ----
__global__ __launch_bounds__(256) void k_mmxb(const float* __restrict__ U, const float* __restrict__ x,
                                              unsigned short* __restrict__ xb,
                                              unsigned* __restrict__ meta, unsigned* __restrict__ fin){
  __shared__ unsigned redA[256], redB[256];
  int t = threadIdx.x, b = blockIdx.x;
  int gid = b*256 + t;
  if (b == 0 && t < 128){ meta[4+t] = 0u; meta[132+t] = 0u; }
  const float4* x4 = (const float4*)x;
  const float4* U4 = (const float4*)U;
  float4 xv[4], uv[8];
  #pragma unroll
  for (int i = 0; i < 4; ++i) xv[i] = x4[gid + i*524288];
  #pragma unroll
  for (int i = 0; i < 8; ++i) uv[i] = U4[gid + i*524288];
  // convert/store x (loads already in flight above)
  #pragma unroll
  for (int i = 0; i < 4; ++i){
    ushort4 o;
    o.x = f2bf(xv[i].x); o.y = f2bf(xv[i].y); o.z = f2bf(xv[i].z); o.w = f2bf(xv[i].w);
    *(ushort4*)(xb + (size_t)(gid + i*524288)*4) = o;
  }
  float mx = -INFINITY, mn = INFINITY;
  #pragma unroll
  for (int i = 0; i < 8; ++i){
    mx = fmaxf(mx, fmaxf(fmaxf(uv[i].x,uv[i].y), fmaxf(uv[i].z,uv[i].w)));
    mn = fminf(mn, fminf(fminf(uv[i].x,uv[i].y), fminf(uv[i].z,uv[i].w)));
  }
  redA[t] = fenc(mx); redB[t] = fenc(mn);
  __syncthreads();
  for (int o = 128; o > 0; o >>= 1){
    if (t < o){ redA[t] = max(redA[t], redA[t+o]); redB[t] = min(redB[t], redB[t+o]); }
    __syncthreads();
  }
  if (t == 0){ atomicMax(&fin[0], redA[0]); atomicMax(&fin[3], ~redB[0]); }
}

// ---- P2: level-2 gmax (-> fin[1]) ----
__global__ __launch_bounds__(256) void k_passA2(const float* __restrict__ U,
                                                unsigned* __restrict__ fin){
  #pragma clang fp contract(off)
  __shared__ unsigned red[256];
  int t = threadIdx.x, b = blockIdx.x;
  float s1 = s1_of(fin);
  float inv_s1 = 1.0f / s1;
  int d0 = (b*256 + t)*4;
  float4 u[8];
  #pragma unroll
  for (int i = 0; i < 8; ++i) u[i] = *(const float4*)(U + (size_t)i*DT + d0);
  unsigned dmax = 0u;
  #pragma unroll
  for (int c = 0; c < 4; ++c){
    float res[8];
    #pragma unroll
    for (int i = 0; i < 8; ++i){
      float uv = ((const float*)&u[i])[c];
      res[i] = uv - base1(uv, s1, inv_s1);
    }
    sort8v(res);
    float m = 0.0f;
    #pragma unroll
    for (int i = 0; i < 7; ++i) m = fmaxf(m, res[i+1] - res[i]);
    dmax = max(dmax, __float_as_uint(m));   // deltas >= 0: bits order-preserving
  }
  red[t] = dmax;
  __syncthreads();
  for (int o = 128; o > 0; o >>= 1){
    if (t < o) red[t] = max(red[t], red[t+o]);
    __syncthreads();
  }
  if (t == 0) atomicMax(&fin[1], red[0]);
}

// ---- P3/P6: codes + histogram (7-ballot match-any: fixed cost) ----
template<int LEVEL>
__global__ __launch_bounds__(256) void k_passB(const float* __restrict__ U,
                                               const unsigned char* __restrict__ mcode,
                                               const float* __restrict__ tm,
                                               unsigned char* __restrict__ code,
                                               unsigned* __restrict__ meta,
                                               const unsigned* __restrict__ fin){
  #pragma clang fp contract(off)
  __shared__ int hist[128];
  int t = threadIdx.x, b = blockIdx.x;
  int lane = t & 63;
  if (t < 128) hist[t] = 0;
  float s1 = s1_of(fin);
  float inv_s1 = 1.0f / s1;
  float s2 = s1 / 5.0f;
  float gmax = __uint_as_float(fin[(LEVEL==2)?1:2]);
  float inv_gmax = 1.0f / gmax;
  int d0 = (b*256 + t)*4;
  float4 u[8], bb[8];
  #pragma unroll
  for (int i = 0; i < 8; ++i){
    u[i] = *(const float4*)(U + (size_t)i*DT + d0);
    if (LEVEL == 2){
      bb[i].x = base1(u[i].x, s1, inv_s1); bb[i].y = base1(u[i].y, s1, inv_s1);
      bb[i].z = base1(u[i].z, s1, inv_s1); bb[i].w = base1(u[i].w, s1, inv_s1);
    } else {
      uchar4 m4 = *(const uchar4*)(mcode + (size_t)i*DT + d0);
      bb[i].x = vn2_of(u[i].x, m4.x, s1, inv_s1, s2);
      bb[i].y = vn2_of(u[i].y, m4.y, s1, inv_s1, s2);
      bb[i].z = vn2_of(u[i].z, m4.z, s1, inv_s1, s2);
      bb[i].w = vn2_of(u[i].w, m4.w, s1, inv_s1, s2);
    }
  }
  __syncthreads();   // hist zeroed before any atomics
  float thr = sigmoid_ref(tm[d0 >> 11]);
  uchar4 cods;
  unsigned char* cp = (unsigned char*)&cods;
  #pragma unroll
  for (int c = 0; c < 4; ++c){
    float res[8];
    #pragma unroll
    for (int i = 0; i < 8; ++i) res[i] = ((const float*)&u[i])[c] - ((const float*)&bb[i])[c];
    sort8v(res);
    int cd = 0;
    #pragma unroll
    for (int i = 0; i < 7; ++i){
      // bit = rint(sigmoid((dn-thr)/0.01)) == (dn > thr)
      float dn = (res[i+1] - res[i]) * inv_gmax;
      cd = (cd << 1) | ((dn > thr) ? 1 : 0);
    }
    cp[c] = (unsigned char)cd;
    // match-any: 7 ballots -> same-code lane mask; one LDS atomic per distinct code
    unsigned long long mset = ~0ull;
    #pragma unroll
    for (int bi = 0; bi < 7; ++bi){
      bool bit = ((cd >> bi) & 1) != 0;
      unsigned long long bbm = __ballot(bit);
      mset &= bit ? bbm : ~bbm;
    }
    int leader = (int)__ffsll(mset) - 1;
    if (lane == leader) atomicAdd(&hist[cd], (int)__popcll(mset));
  }
  *(uchar4*)(code + d0) = cods;
  __syncthreads();
  if (t < 128){ int h = hist[t]; if (h) atomicAdd((int*)&meta[((LEVEL==2)?4:132) + t], h); }
}

// ---- P5/P8: quant apply with REPLICATED rank/top-5/msp preamble (fused old k_small;
//      deterministic: identical inputs -> identical FP sequence in every block).
//   LEVEL==2: nibble-pack scatter in registers, write mcode + fused gmax3.
//   LEVEL==3: per-column 8KB own-lane LDS scatter, write final vsum bf16 [n][k][l]. ----
template<int LEVEL>
__global__ __launch_bounds__(256) void k_passD(const float* __restrict__ U,
                                               unsigned char* __restrict__ mcode,
                                               unsigned short* __restrict__ vsumb,
                                               const unsigned char* __restrict__ code,
                                               const float* __restrict__ tm,
                                               unsigned* __restrict__ meta,
                                               unsigned* __restrict__ fin){
  #pragma clang fp contract(off)
  __shared__ float qcol[8*256];            // LEVEL==3: [row][t] own-lane slots, bank=t%32
  __shared__ unsigned red[256];
  __shared__ int fr_s[128];
  __shared__ unsigned bits_s[128];
  __shared__ float msp_s[896];
  __shared__ int cs[128], rk[128], redk[128];
  __shared__ int top_code[5], top_rank[5];
  __shared__ int w0cnt;
  int t = threadIdx.x, b = blockIdx.x;
  float s1 = s1_of(fin);
  float inv_s1 = 1.0f / s1;
  float s2 = s1 / 5.0f;
  float s  = (LEVEL == 2) ? s2 : (s2 / 17.0f);
  float inv_s = 1.0f / s;
  float gmax = __uint_as_float(fin[(LEVEL==2)?1:2]);

  // --- replicated small preamble (verbatim old k_small logic; 256-thread safe) ---
  {
    int c = t;
    int lane = t & 63;
    if (c < 128){
      cs[c] = (int)meta[((LEVEL==2)?4:132) + c];
      bool present = cs[c] > 0;
      unsigned long long bm = __ballot(present);
      int r = (int)__popcll(bm & ((1ull << lane) - 1ull));
      if (c == 63) w0cnt = (int)__popcll(bm);
      rk[c] = r;
    }
    __syncthreads();
    if (c >= 64 && c < 128) rk[c] += w0cnt;
    __syncthreads();
    for (int k = 0; k < 5; ++k){          // top-5 argsort(-counts), ties -> lowest index
      if (c < 128) redk[c] = (cs[c] << 7) | (127 - c);
      __syncthreads();
      for (int o = 64; o > 0; o >>= 1){
        if (c < o) redk[c] = max(redk[c], redk[c+o]);
        __syncthreads();
      }
      if (c == 0){
        int best = 127 - (redk[0] & 127);
        top_code[k] = best; top_rank[k] = rk[best];
        cs[best] = -1;
      }
      __syncthreads();
    }
    if (c < 128){
      int besti = -1, sel = 0;
      #pragma unroll
      for (int j = 0; j < 5; ++j){        // argmax first-wins over shared-bit counts
        int inter = __popc(c & top_code[j]);
        if (inter > besti){ besti = inter; sel = j; }
      }
      bool is_top = false;
      #pragma unroll
      for (int j = 0; j < 5; ++j) is_top = is_top || (rk[c] == top_rank[j]);
      fr_s[c] = is_top ? rk[c] : top_rank[sel];
      // full-fidelity msp/scheme for col c (scalar U col reads: same lines, L2-broadcast)
      float res[8];
      #pragma unroll
      for (int i = 0; i < 8; ++i){
        size_t off = (size_t)i*DT + c;
        float uu = U[off];
        float bval = (LEVEL==2) ? base1(uu, s1, inv_s1) : vn2_of(uu, mcode[off], s1, inv_s1, s2);
        res[i] = uu - bval;
      }
      sort8v(res);
      float thr = sigmoid_ref(tm[c >> 11]);
      unsigned bits = 0;
      #pragma unroll
      for (int i = 0; i < 7; ++i){
        float dn  = (res[i+1] - res[i]) / gmax;
        float z   = (dn - thr) / 0.01f;
        float msp = sigmoid_ref(z);
        msp_s[c*7 + i] = msp;
        bits |= ((unsigned)(int)rintf(msp)) << i;
      }
      bits_s[c] = bits;
    }
  }
  __syncthreads();   // tables ready

  int d0 = (b*256 + t)*4;
  float4 u4[8];
  uchar4 m4[8];
  #pragma unroll
  for (int i = 0; i < 8; ++i){
    u4[i] = *(const float4*)(U + (size_t)i*DT + d0);
    if (LEVEL == 3) m4[i] = *(const uchar4*)(mcode + (size_t)i*DT + d0);
  }
  uchar4 cods = *(const uchar4*)(code + d0);
  const unsigned char* cp = (const unsigned char*)&cods;
  uchar4 mout[8];
  ushort4 ov[8];
  unsigned dmax = 0u;
  #pragma unroll
  for (int c = 0; c < 4; ++c){
    float v[8]; int ix[8];
    #pragma unroll
    for (int i = 0; i < 8; ++i){
      float uv = ((const float*)&u4[i])[c];
      float bval;
      if (LEVEL == 2) bval = base1(uv, s1, inv_s1);
      else {
        int mi = (int)((const unsigned char*)&m4[i])[c] - 8;
        bval = base1(uv, s1, inv_s1) + s2 * (float)mi;
      }
      v[i] = uv - bval;
      ix[i] = i;
    }
    sort8kv(v, ix);                        // stable: reproduces jnp.argsort
    int cr = fr_s[cp[c]];
    unsigned sb = bits_s[cr];
    float vv[8]; bool bl[8];
    float buf = 0.0f, cnt = 0.0f, g = 1.0f; bool reset = false;
    #pragma unroll
    for (int i = 0; i < 8; ++i){           // reference scan; mean via rcp (<=1.5ulp)
      buf = reset ? v[i] : (buf + v[i]);
      cnt = reset ? 1.0f : (cnt + 1.0f);
      g   = reset ? 1.0f : g;
      float m = buf * __builtin_amdgcn_rcpf(cnt);
      if (i == 7){ vv[7] = g * m; bl[7] = true; }
      else {
        float msp = msp_s[cr*7 + i];
        bool bv = ((sb >> i) & 1u) != 0u;
        vv[i] = bv ? ((g * msp) * m) : 0.0f;
        bl[i] = bv;
        g = bv ? g : (g * (1.0f - msp));
        reset = bv;
      }
    }
    float out = vv[7];
    float inner[8];
    inner[7] = out;
    for (int i = 6; i >= 0; --i){ if (bl[i]) out = vv[i]; inner[i] = out; }
    if (LEVEL == 2){
      // nibble-scatter to original row in registers (verified R2-R6)
      unsigned mp = 0u;
      #pragma unroll
      for (int i = 0; i < 8; ++i){
        float mf = floorf(inner[i] * inv_s);
        int mi = (int)mf;
        mi = max(-8, min(7, mi));
        mp |= (unsigned)(mi + 8) << (4*ix[i]);
      }
      float res3[8];
      #pragma unroll
      for (int r = 0; r < 8; ++r){         // bit-exact next-level residual: u - (b + s*mi)
        int mi = (int)((mp >> (4*r)) & 15u) - 8;
        ((unsigned char*)&mout[r])[c] = (unsigned char)(mi + 8);
        float uv = ((const float*)&u4[r])[c];
        float qv = s * (float)mi;
        float vn = base1(uv, s1, inv_s1) + qv;
        res3[r] = uv - vn;
      }
      sort8v(res3);
      float m = 0.0f;
      #pragma unroll
      for (int i = 0; i < 7; ++i) m = fmaxf(m, res3[i+1] - res3[i]);
      dmax = max(dmax, __float_as_uint(m));
    } else {
      // own-lane LDS scatter (float floor-count, unclamped — verified level-3 path)
      #pragma unroll
      for (int i = 0; i < 8; ++i) qcol[ix[i]*256 + t] = floorf(inner[i] * inv_s);
      #pragma unroll
      for (int r = 0; r < 8; ++r){
        int mi = (int)((const unsigned char*)&m4[r])[c] - 8;
        float uv = ((const float*)&u4[r])[c];
        float bv = base1(uv, s1, inv_s1) + s2 * (float)mi;
        float qv = s * qcol[r*256 + t];
        ((unsigned short*)&ov[r])[c] = f2bf(bv + qv);
      }
    }
  }
  if (LEVEL == 2){
    #pragma unroll
    for (int r = 0; r < 8; ++r)
      *(uchar4*)(mcode + (size_t)r*DT + d0) = mout[r];
    red[t] = dmax;
    __syncthreads();
    for (int o = 128; o > 0; o >>= 1){
      if (t < o) red[t] = max(red[t], red[t+o]);
      __syncthreads();
    }
    if (t == 0) atomicMax(&fin[2], red[0]);
  } else {
    #pragma unroll
    for (int r = 0; r < 8; ++r)
      *(ushort4*)(vsumb + (size_t)r*DT + d0) = ov[r];
  }
}

// transpose: wt[n][l][k] = vsumb[n][k][l] (both bf16); 64(k) x 64(l) tiles
__global__ __launch_bounds__(256) void k_wt(const unsigned short* __restrict__ vsumb,
                                            unsigned short* __restrict__ wt){
  __shared__ unsigned short tile[64][68];
  int t = threadIdx.x;
  int c4 = t & 15, r0 = t >> 4;
  int n = blockIdx.z, k0 = blockIdx.y*64, l0 = blockIdx.x*64;
  const unsigned short* src = vsumb + (size_t)n*DT;
  #pragma unroll
  for (int i = 0; i < 4; ++i){
    int r = r0 + i*16;                     // k index in tile
    ushort4 v = *(const ushort4*)(src + (size_t)(k0+r)*DD2 + l0 + c4*4);
    *(ushort4*)&tile[r][c4*4] = v;
  }
  __syncthreads();
  unsigned short* dst = wt + (size_t)n*DT;
  #pragma unroll
  for (int i = 0; i < 4; ++i){
    int rl = r0 + i*16;                    // l index in tile
    ushort4 o;
    o.x = tile[c4*4+0][rl]; o.y = tile[c4*4+1][rl];
    o.z = tile[c4*4+2][rl]; o.w = tile[c4*4+3][rl];
    *(ushort4*)(dst + (size_t)(l0+rl)*DD1 + k0 + c4*4) = o;
  }
}

// MFMA GEMM: out[b,n,l] = sum_k xb[b,n,k] * wt[n,l,k]; 64(M)x128(N) tile, BK=64, 4 waves
__global__ __launch_bounds__(256) void k_gemm(const unsigned short* __restrict__ xb,
                                              const unsigned short* __restrict__ wt,
                                              float* __restrict__ out){
  __shared__ __align__(16) unsigned short As[64*64];
  __shared__ __align__(16) unsigned short Bs[128*64];
  int t = threadIdx.x;
  int lane = t & 63, wv = t >> 6;
  int n  = blockIdx.z;
  int b0 = blockIdx.y * 64;
  int l0 = blockIdx.x * 128;
  int wm = (wv >> 1) * 32, wn = (wv & 1) * 64;
  int col = lane & 15, quad = lane >> 4;
  int arow = lane >> 3, aseg = lane & 7;
  const unsigned short* wtn = wt + (size_t)n*DT;
  f32x4 acc[2][4] = {};
  for (int k0 = 0; k0 < DD1; k0 += 64){
    #pragma unroll
    for (int i = 0; i < 2; ++i){
      int row = wv*16 + i*8 + arow;
      const unsigned short* g = xb + (((size_t)(b0+row)*NROW + n)*DD1 + k0 + aseg*8);
      async16(g, &As[(wv*16 + i*8)*64]);
    }
    #pragma unroll
    for (int i = 0; i < 4; ++i){
      int row = wv*32 + i*8 + arow;
      const unsigned short* g = wtn + ((size_t)(l0+row)*DD1 + k0 + aseg*8);
      async16(g, &Bs[(wv*32 + i*8)*64]);
    }
    __syncthreads();
    #pragma unroll
    for (int ks = 0; ks < 2; ++ks){
      int kq = ks*32 + quad*8;
      short8 af[2], bfr[4];
      #pragma unroll
      for (int mi = 0; mi < 2; ++mi) af[mi]  = *(const short8*)&As[(wm + mi*16 + col)*64 + kq];
      #pragma unroll
      for (int ni = 0; ni < 4; ++ni) bfr[ni] = *(const short8*)&Bs[(wn + ni*16 + col)*64 + kq];
      #pragma unroll
      for (int mi = 0; mi < 2; ++mi)
        #pragma unroll
        for (int ni = 0; ni < 4; ++ni)
          acc[mi][ni] = __builtin_amdgcn_mfma_f32_16x16x32_bf16(af[mi], bfr[ni], acc[mi][ni], 0, 0, 0);
    }
    __syncthreads();
  }
  #pragma unroll
  for (int mi = 0; mi < 2; ++mi)
    #pragma unroll
    for (int ni = 0; ni < 4; ++ni)
      #pragma unroll
      for (int r = 0; r < 4; ++r){
        int bb = b0 + wm + mi*16 + quad*4 + r;
        int l = l0 + wn + ni*16 + col;
        out[((size_t)bb*NROW + n)*DD2 + l] = acc[mi][ni][r];
      }
}

extern "C" void kernel_launch(void* const* d_in, const int* in_sizes, int n_in,
                              void* d_out, int out_size, void* d_ws, size_t ws_size,
                              hipStream_t stream){
  const float* x  = (const float*)d_in[0];
  const float* U  = (const float*)d_in[1];
  const float* tm = (const float*)d_in[2];
  float* out = (float*)d_out;
  unsigned char*  mcode = (unsigned char*)d_ws;
  unsigned short* vsumb = (unsigned short*)((unsigned char*)d_ws + 16777216);
  unsigned short* xb    = (unsigned short*)((unsigned char*)d_ws + 50331648);
  unsigned char*  code  = (unsigned char*)d_ws + 67108864;
  unsigned short* wt    = (unsigned short*)((unsigned char*)d_ws + 69206016);
  unsigned* meta  = (unsigned*)((unsigned char*)d_ws + 102760448);
  unsigned* fin   = (unsigned*)((unsigned char*)d_ws + 102801408);
  (void)in_sizes; (void)n_in; (void)out_size; (void)ws_size;

  hipMemsetAsync(fin, 0, 16, stream);   // fin[0..3]=0 (min carried as max of ~fenc)
  k_mmxb    <<<NBLK, 256, 0, stream>>>(U, x, xb, meta, fin);
  // level 2 (deno = 5)
  k_passA2  <<<NBLK, 256, 0, stream>>>(U, fin);
  k_passB<2><<<NBLK, 256, 0, stream>>>(U, mcode, tm, code, meta, fin);
  k_passD<2><<<NBLK, 256, 0, stream>>>(U, mcode, vsumb, code, tm, meta, fin);  // + small2 + gmax3
  // level 3 (deno = 17)
  k_passB<3><<<NBLK, 256, 0, stream>>>(U, mcode, tm, code, meta, fin);
  k_passD<3><<<NBLK, 256, 0, stream>>>(U, mcode, vsumb, code, tm, meta, fin);  // + small3
  // epilogue
  k_wt  <<<dim3(DD2/64, DD1/64, NROW), 256, 0, stream>>>(vsumb, wt);
  k_gemm<<<dim3(DD2/128, BATCH/64, NROW), 256, 0, stream>>>(xb, wt, out);
}